// Round 7
// baseline (260.231 us; speedup 1.0000x reference)
//
#include <hip/hip_runtime.h>
#include <hip/hip_bf16.h>

typedef __hip_bfloat16 bf16;
typedef unsigned int uint;
typedef unsigned short ushort;

using frag8 = __attribute__((ext_vector_type(8))) short;   // 8 bf16
using f32x4 = __attribute__((ext_vector_type(4))) float;

#define HWH 784     // 28*28
#define PPITCH 34   // padded plane pitch (shorts); 17 banks (odd) -> conv conflict-free
#define PPLANE 1020 // 34*30 shorts per plane
#define PBLK 12240  // 12*1020 shorts per (b,g)
// image (y,x) lives at (y+1)*34 + (x+2)  => pos = n + 6*(n/28) + 36 (EVEN -> 4B stores)

// ---------------------------------------------------------------------------
// Fold fc_w (9x12) into dep_w (256,9,3,3):  W2[oc][c12][k9]; also biascat.
// ---------------------------------------------------------------------------
__global__ __launch_bounds__(256) void fold_w2(const float* __restrict__ fc_w,
                                               const float* __restrict__ dep_w,
                                               const float* __restrict__ b1,
                                               const float* __restrict__ b2,
                                               const float* __restrict__ b3,
                                               float* __restrict__ W2,
                                               float* __restrict__ biascat) {
    int idx = blockIdx.x * 256 + threadIdx.x;   // oc*108 + c12*9 + k9
    if (idx < 768) {
        const float* bs = idx < 256 ? b1 : (idx < 512 ? b2 : b3);
        biascat[idx] = bs[idx & 255];
    }
    if (idx >= 256 * 108) return;
    int oc  = idx / 108;
    int r   = idx % 108;
    int c12 = r / 9;
    int k9  = r % 9;
    float s = 0.f;
#pragma unroll
    for (int o = 0; o < 9; ++o)
        s += fc_w[o * 12 + c12] * dep_w[oc * 81 + o * 9 + k9];
    W2[idx] = s;
}

// ---------------------------------------------------------------------------
// Weights f32 -> bf16, concatenated [768][256] (q:w1, k:w2, v:w3)
// ---------------------------------------------------------------------------
__global__ __launch_bounds__(256) void wprep(const float* __restrict__ w1,
                                             const float* __restrict__ w2,
                                             const float* __restrict__ w3,
                                             bf16* __restrict__ wbf) {
    int row = blockIdx.x, tid = threadIdx.x;
    const float* src = row < 256 ? w1 : (row < 512 ? w2 : w3);
    wbf[row * 256 + tid] = __float2bfloat16(src[(row & 255) * 256 + tid]);
}

// ---------------------------------------------------------------------------
// x [b][c=256][n=784] f32  ->  xT [b][n=784][c=256] bf16  (32x32 LDS tiles)
// ---------------------------------------------------------------------------
__global__ __launch_bounds__(256) void xpose(const float* __restrict__ x,
                                             bf16* __restrict__ xT) {
    __shared__ float t[32][33];
    const int n0 = blockIdx.x * 32, c0 = blockIdx.y * 32, b = blockIdx.z;
    const int tid = threadIdx.x;
    const float* xb = x + (size_t)b * (256 * HWH);
#pragma unroll
    for (int e = tid; e < 1024; e += 256) {
        int r = e >> 5, col = e & 31;           // r: c-index, col: n-index
        int n = n0 + col;
        t[r][col] = (n < HWH) ? xb[(size_t)(c0 + r) * HWH + n] : 0.f;
    }
    __syncthreads();
#pragma unroll
    for (int e = tid; e < 512; e += 256) {
        int r = e >> 4, cp = (e & 15) * 2;      // r: n-index, cp: c-pair
        int n = n0 + r;
        if (n < HWH) {
            __hip_bfloat162 h;
            h.x = __float2bfloat16(t[cp][r]);
            h.y = __float2bfloat16(t[cp + 1][r]);
            *reinterpret_cast<__hip_bfloat162*>(
                &xT[((size_t)b * HWH + n) * 256 + c0 + cp]) = h;
        }
    }
}

// ---------------------------------------------------------------------------
// MFMA GEMM (R7): 128x128 tile, 2x2 wave grid, 16 KB LDS, 2 barriers/K-step,
// flat grid 2688 with XCD-aware decode (R6: FETCH 79->14 MB, keep).
// NEW in R7: SWAPPED MFMA OPERANDS — acc = mfma(bf, af): C/D transposed so
// lane&15 = m (ONE plane per lane per i) and the 4 regs hold 4 CONSECUTIVE n.
// Epilogue: per i one plane base + one bias; per (i,j) one n/28 and two 4B
// stores (pos even by construction). 64 scalar 2B stores -> 32x 4B, ~4x less
// address VALU. History: single-barrier "B-once" restructures lost (R4/R5);
// (256,6) launch-bounds clamp and full-unroll both spill (R1/R2).
// perm: PADDED pitch-34 planes, image (y,x) at (y+1)*34+(x+2); borders
// garbage, consumers zero halo in LDS.
// m -> sec=m/256, ch=m%256, g=ch%64, head=ch/64, t=sec*4+head.
// ---------------------------------------------------------------------------
__device__ inline void load_lds16(const bf16* g, short* lds) {
    __builtin_amdgcn_global_load_lds(
        (const __attribute__((address_space(1))) void*)g,
        (__attribute__((address_space(3))) void*)lds, 16, 0, 0);
}

__global__ __launch_bounds__(256) void gemm_mfma(const bf16* __restrict__ wbf,
                                                 const float* __restrict__ biascat,
                                                 const bf16* __restrict__ xT,
                                                 bf16* __restrict__ perm) {
    __shared__ short lds[8192];                 // A: [0,4096) shorts, B: [4096,8192)

    const int tid  = threadIdx.x;
    const int wave = tid >> 6, lane = tid & 63;

    // XCD-aware decode: X=s&7 (XCD), j=s>>3, G=X*56+j/6 (n,b group), mt=j%6.
    const int s  = blockIdx.x;
    const int X  = s & 7, j = s >> 3;
    const int G  = X * 56 + j / 6;              // (n,b) group in [0,448)
    const int mt = j % 6;
    const int nt = G % 7;
    const int b  = G / 7;

    const int m0   = mt * 128;
    const int n0   = nt * 128;
    const int mw   = wave & 1, nw = wave >> 1;  // 2x2 wave grid of 64x64 tiles
    const int lrow = lane & 15, lkc = lane >> 4;  // fragment row / k-chunk

    f32x4 acc[4][4] = {};
    const bf16* xb = xT + (size_t)b * (HWH * 256);

    for (int k0 = 0; k0 < 256; k0 += 32) {
#pragma unroll
        for (int i = 0; i < 2; ++i) {
            const int jb = 2 * wave + i;        // fragment-block (16 rows)
            const bf16* ga = wbf + (size_t)(m0 + 16 * jb + lrow) * 256 + k0 + lkc * 8;
            load_lds16(ga, &lds[jb * 512]);
            int n = n0 + 16 * jb + lrow;
            if (n > HWH - 1) n = HWH - 1;       // clamp: OOB cols never stored
            const bf16* gb = xb + (size_t)n * 256 + k0 + lkc * 8;
            load_lds16(gb, &lds[4096 + jb * 512]);
        }
        __syncthreads();

        frag8 af[4], bf_[4];
#pragma unroll
        for (int i = 0; i < 4; ++i)
            af[i] = *reinterpret_cast<const frag8*>(&lds[(4 * mw + i) * 512 + lane * 8]);
#pragma unroll
        for (int j2 = 0; j2 < 4; ++j2)
            bf_[j2] = *reinterpret_cast<const frag8*>(&lds[4096 + (4 * nw + j2) * 512 + lane * 8]);
        // SWAPPED operands: src0 = B-frag, src1 = A-frag  =>  C/D transposed:
        // col(lane&15) = m, regs = 4 consecutive n.
#pragma unroll
        for (int i = 0; i < 4; ++i)
#pragma unroll
            for (int j2 = 0; j2 < 4; ++j2)
                acc[i][j2] = __builtin_amdgcn_mfma_f32_16x16x32_bf16(
                    bf_[j2], af[i], acc[i][j2], 0, 0, 0);
        __syncthreads();
    }

    // Epilogue (swapped layout): lane&15 = m; regs = n_base..n_base+3.
#pragma unroll
    for (int i = 0; i < 4; ++i) {
        const int m = m0 + mw * 64 + i * 16 + lrow;
        const int sec = m >> 8, ch = m & 255;
        bf16* const base = perm + ((size_t)b * 64 + (ch & 63)) * PBLK
                         + (size_t)(sec * 4 + (ch >> 6)) * PPLANE;
        const float bias = biascat[m];
#pragma unroll
        for (int j2 = 0; j2 < 4; ++j2) {
            const int n = n0 + nw * 64 + j2 * 16 + lkc * 4;
            if (n < HWH) {                      // runs of 4 never straddle 784
                const int pos = n + 6 * (n / 28) + 36;   // even => 4B aligned
                __hip_bfloat162 lo, hi;
                lo.x = __float2bfloat16(acc[i][j2][0] + bias);
                lo.y = __float2bfloat16(acc[i][j2][1] + bias);
                hi.x = __float2bfloat16(acc[i][j2][2] + bias);
                hi.y = __float2bfloat16(acc[i][j2][3] + bias);
                *reinterpret_cast<__hip_bfloat162*>(&base[pos])     = lo;
                *reinterpret_cast<__hip_bfloat162*>(&base[pos + 2]) = hi;
            }
        }
    }
}

// ---------------------------------------------------------------------------
// attmean: interior 12x12 window means of v, prescaled by rate1/144.
// attm[b][c][25] f32. One wave per channel; lanes 0..27 own columns.
// v channel c lives at perm[b][c&63][8 + c/64] (bias already included).
// ---------------------------------------------------------------------------
__global__ __launch_bounds__(256) void attmean(const bf16* __restrict__ perm,
                                               const float* __restrict__ rate1,
                                               float* __restrict__ attm) {
    const int b = blockIdx.y, cg = blockIdx.x;            // cg in [0,64)
    const int wave = threadIdx.x >> 6, lane = threadIdx.x & 63;
    const int c = cg * 4 + wave;                          // channel 0..255
    const bf16* vp = perm + ((size_t)(b * 64 + (c & 63)) * 12 + 8 + (c >> 6)) * (size_t)PPLANE;

    float cs[5] = {0.f, 0.f, 0.f, 0.f, 0.f};              // per-wi column sums
    if (lane < 28) {
#pragma unroll
        for (int y = 0; y < 28; ++y) {
            float v = __bfloat162float(vp[(y + 1) * PPITCH + lane + 2]);
#pragma unroll
            for (int wi = 0; wi < 5; ++wi)
                if (y >= 4 * wi && y <= 4 * wi + 11) cs[wi] += v;
        }
    }
    const float r1s = rate1[0] * (1.0f / 144.0f);
#pragma unroll
    for (int wi = 0; wi < 5; ++wi) {
        float p = cs[wi];
#pragma unroll
        for (int d = 1; d < 32; d <<= 1) {                // inclusive prefix over lanes
            float t = __shfl_up(p, d);
            if (lane >= d) p += t;
        }
        float hi = __shfl(p, 4 * lane + 11);              // valid for lane<5
        float lo = __shfl(p, 4 * lane - 1);
        if (lane < 5) {
            float w = hi - (lane ? lo : 0.f);
            attm[((size_t)b * 256 + c) * 25 + wi * 5 + lane] = w * r1s;
        }
    }
}

// ---------------------------------------------------------------------------
// out_fused5: out = att(precomputed means) + rate2 * conv.
// Phase A: straight uint4 copy of 12 padded planes (24.5 KB) + weights + att.
// Phase A2: zero halo borders in LDS (116 shorts/plane, image at x+2).
// Phase C: 3x3 conv, 196 threads x 4 oc x 4 px, pitch 34 (bank stride 17).
// Conv reads 4 uints/row (8 shorts, image cols x0-2..x0+5); rr idx 1..6 used.
// LDS ~27.2 KB -> 5 blocks/CU.
// VGPR history: (256,6) clamp -> 40 VGPR, spill catastrophe (R1).
//               plain bounds + full c-unroll -> 256 VGPR spill (R2).
// Fix: #pragma unroll 1 on the channel loop. DO NOT re-unroll.
// ---------------------------------------------------------------------------
__global__ __launch_bounds__(256) void out_fused5(
    const bf16* __restrict__ perm, const float* __restrict__ W2,
    const float* __restrict__ attm, const float* __restrict__ rate2,
    float* __restrict__ out) {
    __shared__ __align__(16) short planes[12 * PPLANE];   // 24480 B, linear
    __shared__ float w2s[4][12][12];                      // [oc][c][k], k 9->12
    __shared__ float attbs[4][25];

    const int g = blockIdx.x, b = blockIdx.y, tid = threadIdx.x;

    // ---- phase A: linear LDS fill ----
    const uint4* src = (const uint4*)(perm + (size_t)(b * 64 + g) * PBLK);
#pragma unroll
    for (int it = 0; it < 6; ++it) {
        int e = tid + it * 256;                 // 1530 x 16B chunks
        if (e < 1530) ((uint4*)planes)[e] = src[e];
    }
    for (int e = tid; e < 576; e += 256) {
        int oc = e / 144, rem = e % 144, cc = rem / 12, k = rem % 12;
        w2s[oc][cc][k] = (k < 9) ? W2[(4 * g + oc) * 108 + cc * 9 + k] : 0.f;
    }
    if (tid < 100)
        attbs[tid / 25][tid % 25] =
            attm[((size_t)b * 256 + 4 * g + tid / 25) * 25 + tid % 25];
    __syncthreads();

    // ---- phase A2: zero halo borders (global borders hold garbage) ----
    // image cols occupy 2..29; halo = row0/row29 cols 1..30, cols 1&30 rows 1..28
    for (int e = tid; e < 1392; e += 256) {
        int c12 = e / 116, u = e % 116, idx;
        if (u < 30)      idx = u + 1;                       // top row
        else if (u < 60) idx = 29 * PPITCH + (u - 30) + 1;  // bottom row
        else { int v = u - 60; idx = ((v >> 1) + 1) * PPITCH + ((v & 1) ? 30 : 1); }
        planes[c12 * PPLANE + idx] = 0;
    }
    __syncthreads();

    // ---- phase C: conv. Lanes consecutive in y; bank stride 17 (odd). ----
    float acc[4][4] = {};   // [oc][px]
    const int y = tid % 28, xs = tid / 28, x0 = xs * 4;
    if (tid < 196) {
#pragma unroll 1   // CRITICAL: full unroll makes the scheduler hoist all 12
                   // channels' plane loads (~250 live floats) -> spill
        for (int c = 0; c < 12; ++c) {
            float rr[3][8];
#pragma unroll
            for (int dy = 0; dy < 3; ++dy) {
                const uint* row = (const uint*)&planes[c * PPLANE + (y + dy) * PPITCH + x0];
#pragma unroll
                for (int jp = 0; jp < 4; ++jp) {
                    uint w = row[jp];
                    float2 f = __bfloat1622float2(*(const __hip_bfloat162*)&w);
                    rr[dy][2 * jp]     = f.x;
                    rr[dy][2 * jp + 1] = f.y;
                }
            }
#pragma unroll
            for (int oc = 0; oc < 4; ++oc) {
                const float4* wr = reinterpret_cast<const float4*>(&w2s[oc][c][0]);
                float4 wa = wr[0], wb = wr[1], wc = wr[2];
                const float wk[9] = {wa.x, wa.y, wa.z, wa.w, wb.x, wb.y, wb.z, wb.w, wc.x};
#pragma unroll
                for (int ky = 0; ky < 3; ++ky)
#pragma unroll
                    for (int kx = 0; kx < 3; ++kx) {
                        float wv = wk[ky * 3 + kx];
#pragma unroll
                        for (int px = 0; px < 4; ++px)
                            acc[oc][px] += wv * rr[ky][px + kx + 1];
                    }
            }
        }

        // ---- phase D: combine + store (att values ready since phase A) ----
        const float r2 = rate2[0];
        const int wi = (y >> 2) - 1, wj = xs - 1;
        const bool inter = (wi >= 0) & (wi < 5) & (wj >= 0) & (wj < 5);
#pragma unroll
        for (int oc = 0; oc < 4; ++oc) {
            float av = inter ? attbs[oc][wi * 5 + wj] : 0.f;
            float4 o;
            o.x = av + r2 * acc[oc][0];
            o.y = av + r2 * acc[oc][1];
            o.z = av + r2 * acc[oc][2];
            o.w = av + r2 * acc[oc][3];
            *reinterpret_cast<float4*>(
                &out[((size_t)(b * 256 + 4 * g + oc)) * HWH + y * 28 + x0]) = o;
        }
    }
}

// ---------------------------------------------------------------------------
extern "C" void kernel_launch(void* const* d_in, const int* in_sizes, int n_in,
                              void* d_out, int out_size, void* d_ws, size_t ws_size,
                              hipStream_t stream) {
    const float* x     = (const float*)d_in[0];
    const float* w1    = (const float*)d_in[1];
    const float* b1    = (const float*)d_in[2];
    const float* w2    = (const float*)d_in[3];
    const float* b2    = (const float*)d_in[4];
    const float* w3    = (const float*)d_in[5];
    const float* b3    = (const float*)d_in[6];
    const float* fc_w  = (const float*)d_in[7];
    const float* dep_w = (const float*)d_in[8];
    // d_in[9]/d_in[10] = rel_height/rel_width: provably dead (mask collapse)
    const float* rate1 = (const float*)d_in[11];
    const float* rate2 = (const float*)d_in[12];
    float* out = (float*)d_out;

    // workspace layout (bytes):
    //   perm    [0, 100270080)           64*64*12240*2 (PADDED pitch-34 planes)
    //   xT      [100270080, 125960192)   64*784*256*2
    //   attm    = xT base (reused AFTER gemm consumes xT; stream-ordered)
    //   wbf     [125960192, 126353408)   768*256*2
    //   W2      [126353408, 126464000)   256*108*4
    //   biascat [126464000, 126467072)   768*4
    char* wsb = (char*)d_ws;
    bf16*  perm    = (bf16*)wsb;
    bf16*  xT      = (bf16*)(wsb + 100270080);
    float* attm    = (float*)(wsb + 100270080);          // alias of xT
    bf16*  wbf     = (bf16*)(wsb + 125960192);
    float* W2      = (float*)(wsb + 126353408);
    float* biascat = (float*)(wsb + 126464000);

    fold_w2   <<<dim3(108),        dim3(256), 0, stream>>>(fc_w, dep_w, b1, b2, b3, W2, biascat);
    wprep     <<<dim3(768),        dim3(256), 0, stream>>>(w1, w2, w3, wbf);
    xpose     <<<dim3(25, 8, 64),  dim3(256), 0, stream>>>(x, xT);
    gemm_mfma <<<dim3(2688),       dim3(256), 0, stream>>>(wbf, biascat, xT, perm);
    attmean   <<<dim3(64, 64),     dim3(256), 0, stream>>>(perm, rate1, attm);
    out_fused5<<<dim3(64, 64),     dim3(256), 0, stream>>>(perm, W2, attm, rate2, out);
}

// Round 8
// 252.735 us; speedup vs baseline: 1.0297x; 1.0297x over previous
//
#include <hip/hip_runtime.h>
#include <hip/hip_bf16.h>

typedef __hip_bfloat16 bf16;
typedef unsigned int uint;
typedef unsigned short ushort;

using frag8 = __attribute__((ext_vector_type(8))) short;   // 8 bf16
using f32x4 = __attribute__((ext_vector_type(4))) float;

#define HWH 784     // 28*28
#define PPITCH 30   // padded plane pitch (shorts)
#define PPLANE 900  // 30*30 shorts per plane
#define PBLK 10800  // 12*900 shorts per (b,g)

// ---------------------------------------------------------------------------
// Fold fc_w (9x12) into dep_w (256,9,3,3):  W2[oc][c12][k9]; also biascat.
// ---------------------------------------------------------------------------
__global__ __launch_bounds__(256) void fold_w2(const float* __restrict__ fc_w,
                                               const float* __restrict__ dep_w,
                                               const float* __restrict__ b1,
                                               const float* __restrict__ b2,
                                               const float* __restrict__ b3,
                                               float* __restrict__ W2,
                                               float* __restrict__ biascat) {
    int idx = blockIdx.x * 256 + threadIdx.x;   // oc*108 + c12*9 + k9
    if (idx < 768) {
        const float* bs = idx < 256 ? b1 : (idx < 512 ? b2 : b3);
        biascat[idx] = bs[idx & 255];
    }
    if (idx >= 256 * 108) return;
    int oc  = idx / 108;
    int r   = idx % 108;
    int c12 = r / 9;
    int k9  = r % 9;
    float s = 0.f;
#pragma unroll
    for (int o = 0; o < 9; ++o)
        s += fc_w[o * 12 + c12] * dep_w[oc * 81 + o * 9 + k9];
    W2[idx] = s;
}

// ---------------------------------------------------------------------------
// Weights f32 -> bf16, concatenated [768][256] (q:w1, k:w2, v:w3)
// ---------------------------------------------------------------------------
__global__ __launch_bounds__(256) void wprep(const float* __restrict__ w1,
                                             const float* __restrict__ w2,
                                             const float* __restrict__ w3,
                                             bf16* __restrict__ wbf) {
    int row = blockIdx.x, tid = threadIdx.x;
    const float* src = row < 256 ? w1 : (row < 512 ? w2 : w3);
    wbf[row * 256 + tid] = __float2bfloat16(src[(row & 255) * 256 + tid]);
}

// ---------------------------------------------------------------------------
// x [b][c=256][n=784] f32  ->  xT [b][n=784][c=256] bf16  (32x32 LDS tiles)
// ---------------------------------------------------------------------------
__global__ __launch_bounds__(256) void xpose(const float* __restrict__ x,
                                             bf16* __restrict__ xT) {
    __shared__ float t[32][33];
    const int n0 = blockIdx.x * 32, c0 = blockIdx.y * 32, b = blockIdx.z;
    const int tid = threadIdx.x;
    const float* xb = x + (size_t)b * (256 * HWH);
#pragma unroll
    for (int e = tid; e < 1024; e += 256) {
        int r = e >> 5, col = e & 31;           // r: c-index, col: n-index
        int n = n0 + col;
        t[r][col] = (n < HWH) ? xb[(size_t)(c0 + r) * HWH + n] : 0.f;
    }
    __syncthreads();
#pragma unroll
    for (int e = tid; e < 512; e += 256) {
        int r = e >> 4, cp = (e & 15) * 2;      // r: n-index, cp: c-pair
        int n = n0 + r;
        if (n < HWH) {
            __hip_bfloat162 h;
            h.x = __float2bfloat16(t[cp][r]);
            h.y = __float2bfloat16(t[cp + 1][r]);
            *reinterpret_cast<__hip_bfloat162*>(
                &xT[((size_t)b * HWH + n) * 256 + c0 + cp]) = h;
        }
    }
}

// ---------------------------------------------------------------------------
// MFMA GEMM (R8): R6 structure (128x128 tile, 2x2 wave grid, XCD-aware
// decode — FETCH 79->14 MB) + DOUBLE-BUFFERED K-loop.
// Old loop: issue global_load_lds, then immediately __syncthreads() whose
// implicit vmcnt(0) drain exposed full load latency 8x/block (MfmaUtil 12%,
// VALUBusy 12-16%, HBM 20% — latency-bound at ~68 us across 4 variants).
// New loop (T3-minimal): stage(k+1 -> buf^1) issued BEFORE ds_read+MFMA of
// buf; the end-of-step barrier's vmcnt drain is then covered by compute.
// One barrier/step (was 2). Race-free: reads of buf complete (lgkmcnt)
// before the barrier; writes to buf issue only after it.
// R7 lesson: operand-swap epilogue didn't speed gemm (stall isn't epilogue
// VALU) and pitch-34 perm slowed downstream — reverted.
// perm output: PADDED pitch-30 planes, image (y,x) at (y+1)*30+x+1; borders
// garbage, consumers zero halo in LDS.
// m -> sec=m/256, ch=m%256, g=ch%64, head=ch/64, t=sec*4+head.
// ---------------------------------------------------------------------------
__device__ inline void load_lds16(const bf16* g, short* lds) {
    __builtin_amdgcn_global_load_lds(
        (const __attribute__((address_space(1))) void*)g,
        (__attribute__((address_space(3))) void*)lds, 16, 0, 0);
}

__global__ __launch_bounds__(256) void gemm_mfma(const bf16* __restrict__ wbf,
                                                 const float* __restrict__ biascat,
                                                 const bf16* __restrict__ xT,
                                                 bf16* __restrict__ perm) {
    __shared__ short lds[16384];    // 2 buffers of 8192: [A 4096 | B 4096]

    const int tid  = threadIdx.x;
    const int wave = tid >> 6, lane = tid & 63;

    // XCD-aware decode: X=s&7 (XCD), j=s>>3, G=X*56+j/6 (n,b group), mt=j%6.
    const int s  = blockIdx.x;
    const int X  = s & 7, jj = s >> 3;
    const int G  = X * 56 + jj / 6;             // (n,b) group in [0,448)
    const int mt = jj % 6;
    const int nt = G % 7;
    const int b  = G / 7;

    const int m0   = mt * 128;
    const int n0   = nt * 128;
    const int mw   = wave & 1, nw = wave >> 1;  // 2x2 wave grid of 64x64 tiles
    const int lrow = lane & 15, lkc = lane >> 4;  // fragment row / k-chunk

    f32x4 acc[4][4] = {};
    const bf16* xb = xT + (size_t)b * (HWH * 256);

    auto stage = [&](int k0, int boff) {
#pragma unroll
        for (int i = 0; i < 2; ++i) {
            const int jb = 2 * wave + i;        // fragment-block (16 rows)
            const bf16* ga = wbf + (size_t)(m0 + 16 * jb + lrow) * 256 + k0 + lkc * 8;
            load_lds16(ga, &lds[boff + jb * 512]);
            int n = n0 + 16 * jb + lrow;
            if (n > HWH - 1) n = HWH - 1;       // clamp: OOB cols never stored
            const bf16* gb = xb + (size_t)n * 256 + k0 + lkc * 8;
            load_lds16(gb, &lds[boff + 4096 + jb * 512]);
        }
    };

    stage(0, 0);
    __syncthreads();                            // drains prologue staging

    int boff = 0;
#pragma unroll 1
    for (int ks = 0; ks < 8; ++ks) {
        if (ks < 7) stage(32 * (ks + 1), boff ^ 8192);   // issue-early prefetch

        frag8 af[4], bf_[4];
#pragma unroll
        for (int i = 0; i < 4; ++i)
            af[i] = *reinterpret_cast<const frag8*>(
                &lds[boff + (4 * mw + i) * 512 + lane * 8]);
#pragma unroll
        for (int j2 = 0; j2 < 4; ++j2)
            bf_[j2] = *reinterpret_cast<const frag8*>(
                &lds[boff + 4096 + (4 * nw + j2) * 512 + lane * 8]);
#pragma unroll
        for (int i = 0; i < 4; ++i)
#pragma unroll
            for (int j2 = 0; j2 < 4; ++j2)
                acc[i][j2] = __builtin_amdgcn_mfma_f32_16x16x32_bf16(
                    af[i], bf_[j2], acc[i][j2], 0, 0, 0);

        if (ks < 7) __syncthreads();            // one barrier/step; drain is
        boff ^= 8192;                           // covered by the MFMA above
    }

    // Epilogue: C/D layout col=lane&15 (n), row=(lane>>4)*4+reg (m)
    // Store into padded plane position (y+1)*30 + (x+1) = col + 2*(col/28) + 31
#pragma unroll
    for (int i = 0; i < 4; ++i) {
        const int rowb = m0 + mw * 64 + i * 16 + lkc * 4;
        bf16* base[4]; float bias4[4];
#pragma unroll
        for (int r = 0; r < 4; ++r) {
            const int m = rowb + r;
            const int sec = m >> 8, ch = m & 255;
            base[r] = perm + ((size_t)b * 64 + (ch & 63)) * PBLK
                           + (size_t)(sec * 4 + (ch >> 6)) * PPLANE;
            bias4[r] = biascat[m];
        }
#pragma unroll
        for (int j2 = 0; j2 < 4; ++j2) {
            const int col = n0 + nw * 64 + j2 * 16 + lrow;
            if (col < HWH) {
                const int pos = col + 2 * (col / 28) + 31;
#pragma unroll
                for (int r = 0; r < 4; ++r)
                    base[r][pos] = __float2bfloat16(acc[i][j2][r] + bias4[r]);
            }
        }
    }
}

// ---------------------------------------------------------------------------
// attmean: interior 12x12 window means of v, prescaled by rate1/144.
// attm[b][c][25] f32. One wave per channel; lanes 0..27 own columns.
// v channel c lives at perm[b][c&63][8 + c/64] (bias already included).
// ---------------------------------------------------------------------------
__global__ __launch_bounds__(256) void attmean(const bf16* __restrict__ perm,
                                               const float* __restrict__ rate1,
                                               float* __restrict__ attm) {
    const int b = blockIdx.y, cg = blockIdx.x;            // cg in [0,64)
    const int wave = threadIdx.x >> 6, lane = threadIdx.x & 63;
    const int c = cg * 4 + wave;                          // channel 0..255
    const bf16* vp = perm + ((size_t)(b * 64 + (c & 63)) * 12 + 8 + (c >> 6)) * (size_t)PPLANE;

    float cs[5] = {0.f, 0.f, 0.f, 0.f, 0.f};              // per-wi column sums
    if (lane < 28) {
#pragma unroll
        for (int y = 0; y < 28; ++y) {
            float v = __bfloat162float(vp[(y + 1) * PPITCH + lane + 1]);
#pragma unroll
            for (int wi = 0; wi < 5; ++wi)
                if (y >= 4 * wi && y <= 4 * wi + 11) cs[wi] += v;
        }
    }
    const float r1s = rate1[0] * (1.0f / 144.0f);
#pragma unroll
    for (int wi = 0; wi < 5; ++wi) {
        float p = cs[wi];
#pragma unroll
        for (int d = 1; d < 32; d <<= 1) {                // inclusive prefix over lanes
            float t = __shfl_up(p, d);
            if (lane >= d) p += t;
        }
        float hi = __shfl(p, 4 * lane + 11);              // valid for lane<5
        float lo = __shfl(p, 4 * lane - 1);
        if (lane < 5) {
            float w = hi - (lane ? lo : 0.f);
            attm[((size_t)b * 256 + c) * 25 + wi * 5 + lane] = w * r1s;
        }
    }
}

// ---------------------------------------------------------------------------
// out_fused5: out = att(precomputed means) + rate2 * conv.
// Phase A: straight uint4 copy of 12 padded planes (21.6 KB) + weights + att.
// Phase A2: zero halo borders in LDS (116 shorts/plane).
// Phase C: 3x3 conv, 196 threads x 4 oc x 4 px, pitch 30 (bank stride 15).
// LDS ~24.3 KB -> 6 blocks/CU by LDS.
// VGPR history: (256,6) clamp -> 40 VGPR, spill catastrophe (R1).
//               plain bounds + full c-unroll -> 256 VGPR spill (R2).
// Fix: #pragma unroll 1 on the channel loop. DO NOT re-unroll.
// ---------------------------------------------------------------------------
__global__ __launch_bounds__(256) void out_fused5(
    const bf16* __restrict__ perm, const float* __restrict__ W2,
    const float* __restrict__ attm, const float* __restrict__ rate2,
    float* __restrict__ out) {
    __shared__ __align__(16) short planes[12 * PPLANE];   // 21600 B, linear
    __shared__ float w2s[4][12][12];                      // [oc][c][k], k 9->12
    __shared__ float attbs[4][25];

    const int g = blockIdx.x, b = blockIdx.y, tid = threadIdx.x;

    // ---- phase A: linear LDS fill ----
    const uint4* src = (const uint4*)(perm + (size_t)(b * 64 + g) * PBLK);
#pragma unroll
    for (int it = 0; it < 6; ++it) {
        int e = tid + it * 256;                 // 1350 x 16B chunks
        if (e < 1350) ((uint4*)planes)[e] = src[e];
    }
    for (int e = tid; e < 576; e += 256) {
        int oc = e / 144, rem = e % 144, cc = rem / 12, k = rem % 12;
        w2s[oc][cc][k] = (k < 9) ? W2[(4 * g + oc) * 108 + cc * 9 + k] : 0.f;
    }
    if (tid < 100)
        attbs[tid / 25][tid % 25] =
            attm[((size_t)b * 256 + 4 * g + tid / 25) * 25 + tid % 25];
    __syncthreads();

    // ---- phase A2: zero halo borders (global borders hold garbage) ----
    for (int e = tid; e < 1392; e += 256) {
        int c12 = e / 116, u = e % 116, idx;
        if (u < 30)      idx = u;                         // top row
        else if (u < 60) idx = 870 + (u - 30);            // bottom row
        else { int v = u - 60; idx = ((v >> 1) + 1) * PPITCH + (v & 1) * 29; }
        planes[c12 * PPLANE + idx] = 0;
    }
    __syncthreads();

    // ---- phase C: conv. Lanes consecutive in y; bank stride 15 (odd). ----
    float acc[4][4] = {};   // [oc][px]
    const int y = tid % 28, xs = tid / 28, x0 = xs * 4;
    if (tid < 196) {
#pragma unroll 1   // CRITICAL: full unroll makes the scheduler hoist all 12
                   // channels' plane loads (~216 live floats) -> 256 VGPR + spill
        for (int c = 0; c < 12; ++c) {
            float rr[3][6];
#pragma unroll
            for (int dy = 0; dy < 3; ++dy) {
                const uint* row = (const uint*)&planes[c * PPLANE + (y + dy) * PPITCH + x0];
#pragma unroll
                for (int jp = 0; jp < 3; ++jp) {
                    uint w = row[jp];
                    float2 f = __bfloat1622float2(*(const __hip_bfloat162*)&w);
                    rr[dy][2 * jp]     = f.x;
                    rr[dy][2 * jp + 1] = f.y;
                }
            }
#pragma unroll
            for (int oc = 0; oc < 4; ++oc) {
                const float4* wr = reinterpret_cast<const float4*>(&w2s[oc][c][0]);
                float4 wa = wr[0], wb = wr[1], wc = wr[2];
                const float wk[9] = {wa.x, wa.y, wa.z, wa.w, wb.x, wb.y, wb.z, wb.w, wc.x};
#pragma unroll
                for (int ky = 0; ky < 3; ++ky)
#pragma unroll
                    for (int kx = 0; kx < 3; ++kx) {
                        float wv = wk[ky * 3 + kx];
#pragma unroll
                        for (int px = 0; px < 4; ++px)
                            acc[oc][px] += wv * rr[ky][px + kx];
                    }
            }
        }

        // ---- phase D: combine + store (att values ready since phase A) ----
        const float r2 = rate2[0];
        const int wi = (y >> 2) - 1, wj = xs - 1;
        const bool inter = (wi >= 0) & (wi < 5) & (wj >= 0) & (wj < 5);
#pragma unroll
        for (int oc = 0; oc < 4; ++oc) {
            float av = inter ? attbs[oc][wi * 5 + wj] : 0.f;
            float4 o;
            o.x = av + r2 * acc[oc][0];
            o.y = av + r2 * acc[oc][1];
            o.z = av + r2 * acc[oc][2];
            o.w = av + r2 * acc[oc][3];
            *reinterpret_cast<float4*>(
                &out[((size_t)(b * 256 + 4 * g + oc)) * HWH + y * 28 + x0]) = o;
        }
    }
}

// ---------------------------------------------------------------------------
extern "C" void kernel_launch(void* const* d_in, const int* in_sizes, int n_in,
                              void* d_out, int out_size, void* d_ws, size_t ws_size,
                              hipStream_t stream) {
    const float* x     = (const float*)d_in[0];
    const float* w1    = (const float*)d_in[1];
    const float* b1    = (const float*)d_in[2];
    const float* w2    = (const float*)d_in[3];
    const float* b2    = (const float*)d_in[4];
    const float* w3    = (const float*)d_in[5];
    const float* b3    = (const float*)d_in[6];
    const float* fc_w  = (const float*)d_in[7];
    const float* dep_w = (const float*)d_in[8];
    // d_in[9]/d_in[10] = rel_height/rel_width: provably dead (mask collapse)
    const float* rate1 = (const float*)d_in[11];
    const float* rate2 = (const float*)d_in[12];
    float* out = (float*)d_out;

    // workspace layout (bytes):
    //   perm    [0, 88473600)          64*64*12*900*2 (PADDED planes)
    //   xT      [88473600, 114163712)  64*784*256*2
    //   attm    = xT base (reused AFTER gemm consumes xT; stream-ordered)
    //   wbf     [114163712, 114556928) 768*256*2
    //   W2      [114556928, 114667520) 256*108*4
    //   biascat [114667520, 114670592) 768*4
    char* wsb = (char*)d_ws;
    bf16*  perm    = (bf16*)wsb;
    bf16*  xT      = (bf16*)(wsb + 88473600);
    float* attm    = (float*)(wsb + 88473600);           // alias of xT
    bf16*  wbf     = (bf16*)(wsb + 114163712);
    float* W2      = (float*)(wsb + 114556928);
    float* biascat = (float*)(wsb + 114667520);

    fold_w2   <<<dim3(108),        dim3(256), 0, stream>>>(fc_w, dep_w, b1, b2, b3, W2, biascat);
    wprep     <<<dim3(768),        dim3(256), 0, stream>>>(w1, w2, w3, wbf);
    xpose     <<<dim3(25, 8, 64),  dim3(256), 0, stream>>>(x, xT);
    gemm_mfma <<<dim3(2688),       dim3(256), 0, stream>>>(wbf, biascat, xT, perm);
    attmean   <<<dim3(64, 64),     dim3(256), 0, stream>>>(perm, rate1, attm);
    out_fused5<<<dim3(64, 64),     dim3(256), 0, stream>>>(perm, W2, attm, rate2, out);
}